// Round 1
// baseline (597.991 us; speedup 1.0000x reference)
//
#include <hip/hip_runtime.h>
#include <stdint.h>

// Blocked attention (per-key-block softmax, outputs summed over key blocks).
// B=2, H=16, S=2048, D=128, softmax block = 256 keys.
// Strategy: bf16 MFMA (16x16x32) for QK^T and PV, fp32 accumulate.
// WG = 256 threads (4 waves), 64 query rows per WG (16 per wave).
// K/V processed in 64-key chunks through a shared LDS buffer.

#define S_LEN 2048
#define D_DIM 128
#define BS 256
#define QT 64
#define WQ 16
#define CK 64
#define QS 136   // sQ / sK row stride (elems): 136*2B = 272B = 68 banks == 4 mod 32 -> 2-way on b128
#define VS 72    // sVt row stride: 144B = 36 banks == 4 mod 32 -> 2-way
#define PS 72    // sP row stride

typedef __attribute__((ext_vector_type(8))) short bf16x8;
typedef __attribute__((ext_vector_type(4))) short bf16x4;
typedef __attribute__((ext_vector_type(4))) float f32x4;

__device__ __forceinline__ short f2bf(float f) {
  union { float f; uint32_t u; } c; c.f = f;
  uint32_t u = c.u;
  u += 0x7fffu + ((u >> 16) & 1u);   // RNE to bf16
  return (short)(u >> 16);
}

__global__ __launch_bounds__(256, 2) void blocked_attn(
    const float* __restrict__ Q, const float* __restrict__ K,
    const float* __restrict__ V, float* __restrict__ O) {
  __shared__ short sQ[QT * QS];       // 17408 B
  __shared__ short sKV[D_DIM * VS];   // 18432 B: K chunk (64x136=8704) or Vt (128x72=9216)
  __shared__ short sP[QT * PS];       // 9216 B
  // total 45056 B -> 3 blocks/CU by LDS

  const int tid  = threadIdx.x;
  const int wave = tid >> 6;
  const int lane = tid & 63;
  const int l15  = lane & 15;
  const int quad = lane >> 4;

  const int bh = blockIdx.y;
  const int q0 = blockIdx.x * QT;
  const size_t hoff = (size_t)bh * S_LEN * D_DIM;
  const float* Qg = Q + hoff + (size_t)q0 * D_DIM;
  const float* Kg = K + hoff;
  const float* Vg = V + hoff;
  float*       Og = O + hoff + (size_t)q0 * D_DIM;

  // ---- stage Q (64x128 fp32 -> bf16 LDS) ----
#pragma unroll
  for (int i = 0; i < 8; ++i) {
    int e = i * 256 + tid;
    int row = e >> 5;
    int c4 = (e & 31) << 2;
    f32x4 v = *(const f32x4*)(Qg + row * D_DIM + c4);
    bf16x4 s; s[0]=f2bf(v[0]); s[1]=f2bf(v[1]); s[2]=f2bf(v[2]); s[3]=f2bf(v[3]);
    *(bf16x4*)&sQ[row * QS + c4] = s;
  }
  __syncthreads();

  // cache this wave's Q A-fragments (rows wave*16 + (lane&15), k = ks*32 + quad*8..+7)
  bf16x8 qf[4];
#pragma unroll
  for (int ks = 0; ks < 4; ++ks)
    qf[ks] = *(const bf16x8*)&sQ[(wave * WQ + l15) * QS + ks * 32 + quad * 8];

  f32x4 oacc[8];
#pragma unroll
  for (int nt = 0; nt < 8; ++nt) { oacc[nt][0]=0.f; oacc[nt][1]=0.f; oacc[nt][2]=0.f; oacc[nt][3]=0.f; }

  const float scale = 0.08838834764831845f;  // 128^-0.5

  for (int j = 0; j < 8; ++j) {
    const float* Kb = Kg + j * BS * D_DIM;
    const float* Vb = Vg + j * BS * D_DIM;

    f32x4 sc[16];
#pragma unroll
    for (int t = 0; t < 16; ++t) { sc[t][0]=0.f; sc[t][1]=0.f; sc[t][2]=0.f; sc[t][3]=0.f; }

    // ---- scores S = Q K^T over 4 chunks of 64 keys ----
    for (int c = 0; c < 4; ++c) {
      __syncthreads();  // protect sKV from previous consumers
#pragma unroll
      for (int i = 0; i < 8; ++i) {
        int e = i * 256 + tid;
        int row = e >> 5;
        int c4 = (e & 31) << 2;
        f32x4 v = *(const f32x4*)(Kb + (c * CK + row) * D_DIM + c4);
        bf16x4 s; s[0]=f2bf(v[0]); s[1]=f2bf(v[1]); s[2]=f2bf(v[2]); s[3]=f2bf(v[3]);
        *(bf16x4*)&sKV[row * QS + c4] = s;
      }
      __syncthreads();
#pragma unroll
      for (int ct = 0; ct < 4; ++ct) {
        f32x4 acc = sc[c * 4 + ct];
#pragma unroll
        for (int ks = 0; ks < 4; ++ks) {
          bf16x8 b = *(const bf16x8*)&sKV[(ct * 16 + l15) * QS + ks * 32 + quad * 8];
          acc = __builtin_amdgcn_mfma_f32_16x16x32_bf16(qf[ks], b, acc, 0, 0, 0);
        }
        sc[c * 4 + ct] = acc;
      }
    }

    // ---- per-row softmax over the 256 keys of this block ----
    // lane holds rows quad*4+r (r=0..3), col = t*16 + (lane&15)
    float mx[4], sm[4];
#pragma unroll
    for (int r = 0; r < 4; ++r) {
      float m = -3.0e38f;
#pragma unroll
      for (int t = 0; t < 16; ++t) m = fmaxf(m, sc[t][r]);
      m = fmaxf(m, __shfl_xor(m, 1));
      m = fmaxf(m, __shfl_xor(m, 2));
      m = fmaxf(m, __shfl_xor(m, 4));
      m = fmaxf(m, __shfl_xor(m, 8));
      mx[r] = m; sm[r] = 0.f;
    }
#pragma unroll
    for (int t = 0; t < 16; ++t) {
#pragma unroll
      for (int r = 0; r < 4; ++r) {
        float p = __expf((sc[t][r] - mx[r]) * scale);
        sc[t][r] = p;
        sm[r] += p;
      }
    }
#pragma unroll
    for (int r = 0; r < 4; ++r) {
      float s = sm[r];
      s += __shfl_xor(s, 1);
      s += __shfl_xor(s, 2);
      s += __shfl_xor(s, 4);
      s += __shfl_xor(s, 8);
      sm[r] = 1.0f / s;
    }
#pragma unroll
    for (int t = 0; t < 16; ++t)
#pragma unroll
      for (int r = 0; r < 4; ++r) sc[t][r] *= sm[r];

    // ---- O += P V over 4 chunks of 64 keys ----
    for (int c = 0; c < 4; ++c) {
      __syncthreads();  // previous chunk's sP/sKV consumers done
      // write this wave's P chunk (C-layout -> LDS, rows wave*16+quad*4+r)
#pragma unroll
      for (int ct2 = 0; ct2 < 4; ++ct2) {
#pragma unroll
        for (int r = 0; r < 4; ++r) {
          sP[(wave * WQ + quad * 4 + r) * PS + ct2 * 16 + l15] = f2bf(sc[c * 4 + ct2][r]);
        }
      }
      // load V chunk transposed: sVt[d][k_local]
#pragma unroll
      for (int i = 0; i < 8; ++i) {
        int e = i * 256 + tid;
        int krow = e >> 5;
        int c4 = (e & 31) << 2;
        f32x4 v = *(const f32x4*)(Vb + (c * CK + krow) * D_DIM + c4);
#pragma unroll
        for (int jj = 0; jj < 4; ++jj)
          sKV[(c4 + jj) * VS + krow] = f2bf(v[jj]);
      }
      __syncthreads();
#pragma unroll
      for (int ks = 0; ks < 2; ++ks) {
        bf16x8 a = *(const bf16x8*)&sP[(wave * WQ + l15) * PS + ks * 32 + quad * 8];
#pragma unroll
        for (int nt = 0; nt < 8; ++nt) {
          bf16x8 b = *(const bf16x8*)&sKV[(nt * 16 + l15) * VS + ks * 32 + quad * 8];
          oacc[nt] = __builtin_amdgcn_mfma_f32_16x16x32_bf16(a, b, oacc[nt], 0, 0, 0);
        }
      }
    }
  }

  // ---- epilogue: O rows quad*4+r, cols nt*16 + (lane&15) ----
#pragma unroll
  for (int nt = 0; nt < 8; ++nt) {
#pragma unroll
    for (int r = 0; r < 4; ++r) {
      Og[(wave * WQ + quad * 4 + r) * D_DIM + nt * 16 + l15] = oacc[nt][r];
    }
  }
}

extern "C" void kernel_launch(void* const* d_in, const int* in_sizes, int n_in,
                              void* d_out, int out_size, void* d_ws, size_t ws_size,
                              hipStream_t stream) {
  const float* Q = (const float*)d_in[0];
  const float* K = (const float*)d_in[1];
  const float* V = (const float*)d_in[2];
  float* O = (float*)d_out;
  const int BH = in_sizes[0] / (S_LEN * D_DIM);  // 32
  dim3 grid(S_LEN / QT, BH, 1);
  blocked_attn<<<grid, 256, 0, stream>>>(Q, K, V, O);
}

// Round 2
// 294.279 us; speedup vs baseline: 2.0321x; 2.0321x over previous
//
#include <hip/hip_runtime.h>
#include <stdint.h>

#define S_LEN 2048
#define D_DIM 128

typedef __attribute__((ext_vector_type(8))) short bf16x8;
typedef __attribute__((ext_vector_type(4))) short bf16x4;
typedef __attribute__((ext_vector_type(4))) float f32x4;

__device__ __forceinline__ short f2bf(float f) {
  union { float f; uint32_t u; } c; c.f = f;
  uint32_t u = c.u;
  u += 0x7fffu + ((u >> 16) & 1u);   // RNE to bf16
  return (short)(u >> 16);
}

__device__ __forceinline__ void gl_lds16(const short* g, short* l) {
  __builtin_amdgcn_global_load_lds((const __attribute__((address_space(1))) void*)g,
                                   (__attribute__((address_space(3))) void*)l, 16, 0, 0);
}

// ---------------- preprocess: fp32 -> bf16 (optionally scaled) ----------------
__global__ __launch_bounds__(256) void cvt_bf16_scale(const float* __restrict__ src,
                                                      short* __restrict__ dst,
                                                      float scale, int n4) {
  int i = blockIdx.x * 256 + threadIdx.x;
  if (i >= n4) return;
  f32x4 v = ((const f32x4*)src)[i];
  bf16x4 o;
  o[0] = f2bf(v[0] * scale); o[1] = f2bf(v[1] * scale);
  o[2] = f2bf(v[2] * scale); o[3] = f2bf(v[3] * scale);
  ((bf16x4*)dst)[i] = o;
}

// ---------------- preprocess: V [bh][k][d] fp32 -> Vt [bh][d][k] bf16 ----------------
__global__ __launch_bounds__(256) void transpose_v(const float* __restrict__ V,
                                                   short* __restrict__ Vt) {
  __shared__ __align__(16) short sT[128 * 136];
  const int bh = blockIdx.y;
  const int k0 = blockIdx.x * 128;
  const float* src = V + ((size_t)bh * S_LEN + k0) * D_DIM;
#pragma unroll
  for (int i = 0; i < 16; ++i) {
    int idx = i * 1024 + threadIdx.x * 4;
    int row = idx >> 7, col = idx & 127;
    f32x4 v = *(const f32x4*)(src + row * D_DIM + col);
    bf16x4 o;
    o[0] = f2bf(v[0]); o[1] = f2bf(v[1]); o[2] = f2bf(v[2]); o[3] = f2bf(v[3]);
    *(bf16x4*)&sT[row * 136 + col] = o;
  }
  __syncthreads();
  const int d = threadIdx.x >> 1;
  const int kh = (threadIdx.x & 1) * 64;
  short* out = Vt + ((size_t)bh * D_DIM + d) * S_LEN + k0 + kh;
#pragma unroll
  for (int g = 0; g < 8; ++g) {
    bf16x8 o;
#pragma unroll
    for (int t = 0; t < 8; ++t) o[t] = sT[(kh + g * 8 + t) * 136 + d];
    *(bf16x8*)(out + g * 8) = o;
  }
}

// ---------------- main blocked-attention kernel ----------------
// WG: 256 thr / 4 waves, 64 q-rows. Per 256-key j-block: QK^T (waves slice keys),
// per-key-block softmax (no max-sub; Q prescaled by scale*log2e), PV (waves slice d).
// K/Vt staged in 64-key chunks via global_load_lds(16B), XOR-granule swizzled LDS.
__global__ __launch_bounds__(256, 2) void attn_main(
    const short* __restrict__ Qb, const short* __restrict__ Kb,
    const short* __restrict__ Vtb, float* __restrict__ O) {
  __shared__ __align__(16) short sStage[2][8192];  // 2 x 16 KB
  __shared__ __align__(16) short sP[16384];        // 64 x 256 bf16, swizzled
  __shared__ f32x4 sRedV[64];                      // per-row partial sums (4 waves)

  const int tid  = threadIdx.x;
  const int w    = tid >> 6;
  const int lane = tid & 63;
  const int l15  = lane & 15;
  const int quad = lane >> 4;
  const int bh = blockIdx.y;
  const int q0 = blockIdx.x * 64;

  const short* Kh = Kb + (size_t)bh * S_LEN * D_DIM;
  const short* Vh = Vtb + (size_t)bh * D_DIM * S_LEN;

  // staging lane constants (granule-XOR-swizzled source addressing)
  const int kKey = tid >> 4;                    // + r*16
  const int kG   = (tid & 15) ^ (kKey & 7);
  const int vD   = tid >> 3;                    // + r*32
  const int vG   = (tid & 7) ^ (vD & 7);
  short* dst0 = &sStage[0][tid * 8];
  short* dst1 = &sStage[1][tid * 8];

  // Q fragments, register-resident for the whole kernel
  bf16x8 qf[4][4];
  {
    const short* Qh = Qb + ((size_t)bh * S_LEN + q0) * D_DIM;
#pragma unroll
    for (int m = 0; m < 4; ++m)
#pragma unroll
      for (int ks = 0; ks < 4; ++ks)
        qf[m][ks] = *(const bf16x8*)(Qh + (m * 16 + l15) * D_DIM + ks * 32 + quad * 8);
  }

  // precomputed swizzled LDS fragment offsets (shorts)
  int kboff[4];
#pragma unroll
  for (int ks = 0; ks < 4; ++ks)
    kboff[ks] = (w * 16 + l15) * 128 + (((ks * 4 + quad) ^ (l15 & 7)) << 3);
  int paoff[4][2];
#pragma unroll
  for (int m = 0; m < 4; ++m)
#pragma unroll
    for (int ks2 = 0; ks2 < 2; ++ks2)
      paoff[m][ks2] = (m * 16 + l15) * 256 + (((ks2 * 4 + quad) ^ (l15 & 7)) << 3);
  int vboff[2][2];
#pragma unroll
  for (int nt = 0; nt < 2; ++nt)
#pragma unroll
    for (int ks2 = 0; ks2 < 2; ++ks2)
      vboff[nt][ks2] = (w * 32 + nt * 16 + l15) * 64 + (((ks2 * 4 + quad) ^ (l15 & 7)) << 3);

  f32x4 oa[4][2];
#pragma unroll
  for (int m = 0; m < 4; ++m)
#pragma unroll
    for (int nt = 0; nt < 2; ++nt) oa[m][nt] = (f32x4){0.f, 0.f, 0.f, 0.f};

  auto stageK = [&](int key0, short* dst) {
    const short* src = Kh + (size_t)(key0 + kKey) * D_DIM + kG * 8;
#pragma unroll
    for (int r = 0; r < 4; ++r) gl_lds16(src + r * 2048, dst + r * 2048);
  };
  auto stageV = [&](int key0, short* dst) {
    const short* src = Vh + (size_t)vD * S_LEN + key0 + vG * 8;
#pragma unroll
    for (int r = 0; r < 4; ++r) gl_lds16(src + (size_t)r * 32 * S_LEN, dst + r * 2048);
  };

  stageK(0, dst0);  // prologue: j0 K chunk 0 -> buf0

  for (int j = 0; j < 8; ++j) {
    const int jb = j * 256;
    f32x4 sc[4][4];
#pragma unroll
    for (int m = 0; m < 4; ++m)
#pragma unroll
      for (int cc = 0; cc < 4; ++cc) sc[m][cc] = (f32x4){0.f, 0.f, 0.f, 0.f};

    // ---- QK^T: 4 chunks of 64 keys; wave w owns keys [c*64+w*16, +16) ----
#pragma unroll
    for (int c = 0; c < 4; ++c) {
      __syncthreads();  // chunk c staged (vmcnt drain) + other buf free
      if (c < 3) stageK(jb + (c + 1) * 64, (c & 1) ? dst0 : dst1);
      else       stageV(jb, dst0);
      const short* buf = &sStage[c & 1][0];
#pragma unroll
      for (int ks = 0; ks < 4; ++ks) {
        bf16x8 b = *(const bf16x8*)(buf + kboff[ks]);
#pragma unroll
        for (int m = 0; m < 4; ++m)
          sc[m][c] = __builtin_amdgcn_mfma_f32_16x16x32_bf16(qf[m][ks], b, sc[m][c], 0, 0, 0);
      }
    }

    // ---- per-key-block softmax (scores prescaled by scale*log2e -> exp2) ----
#pragma unroll
    for (int m = 0; m < 4; ++m)
#pragma unroll
      for (int cc = 0; cc < 4; ++cc)
#pragma unroll
        for (int r = 0; r < 4; ++r) sc[m][cc][r] = exp2f(sc[m][cc][r]);

    float rs[4][4];
#pragma unroll
    for (int m = 0; m < 4; ++m) {
      f32x4 t = sc[m][0] + sc[m][1] + sc[m][2] + sc[m][3];
#pragma unroll
      for (int r = 0; r < 4; ++r) {
        float v = t[r];
        v += __shfl_xor(v, 1);
        v += __shfl_xor(v, 2);
        v += __shfl_xor(v, 4);
        v += __shfl_xor(v, 8);
        rs[m][r] = v;
      }
    }
    if (l15 == 0) {
#pragma unroll
      for (int m = 0; m < 4; ++m)
#pragma unroll
        for (int r = 0; r < 4; ++r) sRedV[m * 16 + quad * 4 + r][w] = rs[m][r];
    }
    __syncthreads();
    float linv[4][4];
#pragma unroll
    for (int m = 0; m < 4; ++m)
#pragma unroll
      for (int r = 0; r < 4; ++r) {
        f32x4 v = sRedV[m * 16 + quad * 4 + r];
        linv[m][r] = __fdividef(1.0f, v[0] + v[1] + v[2] + v[3]);
      }
    // write normalized P (bf16) to swizzled sP
#pragma unroll
    for (int m = 0; m < 4; ++m) {
#pragma unroll
      for (int r = 0; r < 4; ++r) {
        const int rw = m * 16 + quad * 4 + r;
        const int rb = rw & 7;
        const int base = rw * 256 + (l15 & 7);
        const int gl = (w * 2 + (l15 >> 3)) ^ rb;
#pragma unroll
        for (int cc = 0; cc < 4; ++cc)
          sP[base + (cc * 8 + gl) * 8] = f2bf(sc[m][cc][r] * linv[m][r]);
      }
    }
    __syncthreads();  // sP ready; Vt chunk 0 staged

    // ---- PV: 4 chunks of 64 keys; wave w owns d-slice [w*32, +32) ----
#pragma unroll
    for (int c = 0; c < 4; ++c) {
      if (c) __syncthreads();
      if (c < 3)      stageV(jb + (c + 1) * 64, (c & 1) ? dst0 : dst1);
      else if (j < 7) stageK(jb + 256, dst0);
      const short* buf = &sStage[c & 1][0];
#pragma unroll
      for (int ks2 = 0; ks2 < 2; ++ks2) {
        bf16x8 a[4];
#pragma unroll
        for (int m = 0; m < 4; ++m)
          a[m] = *(const bf16x8*)(sP + paoff[m][ks2] + c * 64);
#pragma unroll
        for (int nt = 0; nt < 2; ++nt) {
          bf16x8 b = *(const bf16x8*)(buf + vboff[nt][ks2]);
#pragma unroll
          for (int m = 0; m < 4; ++m)
            oa[m][nt] = __builtin_amdgcn_mfma_f32_16x16x32_bf16(a[m], b, oa[m][nt], 0, 0, 0);
        }
      }
    }
  }

  // ---- epilogue ----
  float* Og = O + ((size_t)bh * S_LEN + q0) * D_DIM;
#pragma unroll
  for (int m = 0; m < 4; ++m)
#pragma unroll
    for (int nt = 0; nt < 2; ++nt)
#pragma unroll
      for (int r = 0; r < 4; ++r)
        Og[(m * 16 + quad * 4 + r) * D_DIM + w * 32 + nt * 16 + l15] = oa[m][nt][r];
}

// ---------------- fallback (round-1 kernel, used if ws too small) ----------------
#define QT 64
#define WQ 16
#define CK 64
#define QS 136
#define VS 72
#define PS 72
#define BS 256

__global__ __launch_bounds__(256, 2) void blocked_attn(
    const float* __restrict__ Q, const float* __restrict__ K,
    const float* __restrict__ V, float* __restrict__ O) {
  __shared__ short sQ[QT * QS];
  __shared__ short sKV[D_DIM * VS];
  __shared__ short sP2[QT * PS];

  const int tid  = threadIdx.x;
  const int wave = tid >> 6;
  const int lane = tid & 63;
  const int l15  = lane & 15;
  const int quad = lane >> 4;

  const int bh = blockIdx.y;
  const int q0 = blockIdx.x * QT;
  const size_t hoff = (size_t)bh * S_LEN * D_DIM;
  const float* Qg = Q + hoff + (size_t)q0 * D_DIM;
  const float* Kg = K + hoff;
  const float* Vg = V + hoff;
  float*       Og = O + hoff + (size_t)q0 * D_DIM;

#pragma unroll
  for (int i = 0; i < 8; ++i) {
    int e = i * 256 + tid;
    int row = e >> 5;
    int c4 = (e & 31) << 2;
    f32x4 v = *(const f32x4*)(Qg + row * D_DIM + c4);
    bf16x4 s; s[0]=f2bf(v[0]); s[1]=f2bf(v[1]); s[2]=f2bf(v[2]); s[3]=f2bf(v[3]);
    *(bf16x4*)&sQ[row * QS + c4] = s;
  }
  __syncthreads();

  bf16x8 qf[4];
#pragma unroll
  for (int ks = 0; ks < 4; ++ks)
    qf[ks] = *(const bf16x8*)&sQ[(wave * WQ + l15) * QS + ks * 32 + quad * 8];

  f32x4 oacc[8];
#pragma unroll
  for (int nt = 0; nt < 8; ++nt) { oacc[nt][0]=0.f; oacc[nt][1]=0.f; oacc[nt][2]=0.f; oacc[nt][3]=0.f; }

  const float scale = 0.08838834764831845f;

  for (int j = 0; j < 8; ++j) {
    const float* Kb = Kg + j * BS * D_DIM;
    const float* Vb = Vg + j * BS * D_DIM;
    f32x4 sc[16];
#pragma unroll
    for (int t = 0; t < 16; ++t) { sc[t][0]=0.f; sc[t][1]=0.f; sc[t][2]=0.f; sc[t][3]=0.f; }

    for (int c = 0; c < 4; ++c) {
      __syncthreads();
#pragma unroll
      for (int i = 0; i < 8; ++i) {
        int e = i * 256 + tid;
        int row = e >> 5;
        int c4 = (e & 31) << 2;
        f32x4 v = *(const f32x4*)(Kb + (c * CK + row) * D_DIM + c4);
        bf16x4 s; s[0]=f2bf(v[0]); s[1]=f2bf(v[1]); s[2]=f2bf(v[2]); s[3]=f2bf(v[3]);
        *(bf16x4*)&sKV[row * QS + c4] = s;
      }
      __syncthreads();
#pragma unroll
      for (int ct = 0; ct < 4; ++ct) {
        f32x4 acc = sc[c * 4 + ct];
#pragma unroll
        for (int ks = 0; ks < 4; ++ks) {
          bf16x8 b = *(const bf16x8*)&sKV[(ct * 16 + l15) * QS + ks * 32 + quad * 8];
          acc = __builtin_amdgcn_mfma_f32_16x16x32_bf16(qf[ks], b, acc, 0, 0, 0);
        }
        sc[c * 4 + ct] = acc;
      }
    }

    float mx[4], sm[4];
#pragma unroll
    for (int r = 0; r < 4; ++r) {
      float m = -3.0e38f;
#pragma unroll
      for (int t = 0; t < 16; ++t) m = fmaxf(m, sc[t][r]);
      m = fmaxf(m, __shfl_xor(m, 1));
      m = fmaxf(m, __shfl_xor(m, 2));
      m = fmaxf(m, __shfl_xor(m, 4));
      m = fmaxf(m, __shfl_xor(m, 8));
      mx[r] = m; sm[r] = 0.f;
    }
#pragma unroll
    for (int t = 0; t < 16; ++t)
#pragma unroll
      for (int r = 0; r < 4; ++r) {
        float p = __expf((sc[t][r] - mx[r]) * scale);
        sc[t][r] = p;
        sm[r] += p;
      }
#pragma unroll
    for (int r = 0; r < 4; ++r) {
      float s = sm[r];
      s += __shfl_xor(s, 1);
      s += __shfl_xor(s, 2);
      s += __shfl_xor(s, 4);
      s += __shfl_xor(s, 8);
      sm[r] = 1.0f / s;
    }
#pragma unroll
    for (int t = 0; t < 16; ++t)
#pragma unroll
      for (int r = 0; r < 4; ++r) sc[t][r] *= sm[r];

    for (int c = 0; c < 4; ++c) {
      __syncthreads();
#pragma unroll
      for (int ct2 = 0; ct2 < 4; ++ct2)
#pragma unroll
        for (int r = 0; r < 4; ++r)
          sP2[(wave * WQ + quad * 4 + r) * PS + ct2 * 16 + l15] = f2bf(sc[c * 4 + ct2][r]);
#pragma unroll
      for (int i = 0; i < 8; ++i) {
        int e = i * 256 + tid;
        int krow = e >> 5;
        int c4 = (e & 31) << 2;
        f32x4 v = *(const f32x4*)(Vb + (c * CK + krow) * D_DIM + c4);
#pragma unroll
        for (int jj = 0; jj < 4; ++jj)
          sKV[(c4 + jj) * VS + krow] = f2bf(v[jj]);
      }
      __syncthreads();
#pragma unroll
      for (int ks = 0; ks < 2; ++ks) {
        bf16x8 a = *(const bf16x8*)&sP2[(wave * WQ + l15) * PS + ks * 32 + quad * 8];
#pragma unroll
        for (int nt = 0; nt < 8; ++nt) {
          bf16x8 b = *(const bf16x8*)&sKV[(nt * 16 + l15) * VS + ks * 32 + quad * 8];
          oacc[nt] = __builtin_amdgcn_mfma_f32_16x16x32_bf16(a, b, oacc[nt], 0, 0, 0);
        }
      }
    }
  }

#pragma unroll
  for (int nt = 0; nt < 8; ++nt)
#pragma unroll
    for (int r = 0; r < 4; ++r)
      Og[(wave * WQ + quad * 4 + r) * D_DIM + nt * 16 + l15] = oacc[nt][r];
}

extern "C" void kernel_launch(void* const* d_in, const int* in_sizes, int n_in,
                              void* d_out, int out_size, void* d_ws, size_t ws_size,
                              hipStream_t stream) {
  const float* Q = (const float*)d_in[0];
  const float* K = (const float*)d_in[1];
  const float* V = (const float*)d_in[2];
  float* Out = (float*)d_out;
  const int bhN = in_sizes[0] / (S_LEN * D_DIM);
  const size_t tElems = (size_t)bhN * S_LEN * D_DIM;
  const size_t need = tElems * 2 * 3;  // 3 bf16 tensors

  if (ws_size >= need) {
    short* Qb  = (short*)d_ws;
    short* Kb  = Qb + tElems;
    short* Vtb = Kb + tElems;
    const int n4 = (int)(tElems / 4);
    const float QSCALE = (float)(0.08838834764831845 * 1.4426950408889634);  // D^-0.5 * log2(e)
    cvt_bf16_scale<<<(n4 + 255) / 256, 256, 0, stream>>>(Q, Qb, QSCALE, n4);
    cvt_bf16_scale<<<(n4 + 255) / 256, 256, 0, stream>>>(K, Kb, 1.0f, n4);
    transpose_v<<<dim3(S_LEN / 128, bhN), 256, 0, stream>>>(V, Vtb);
    attn_main<<<dim3(S_LEN / 64, bhN), 256, 0, stream>>>(Qb, Kb, Vtb, Out);
  } else {
    blocked_attn<<<dim3(S_LEN / 64, bhN), 256, 0, stream>>>(Q, K, V, Out);
  }
}